// Round 2
// baseline (1514.659 us; speedup 1.0000x reference)
//
#include <hip/hip_runtime.h>
#include <hip/hip_bf16.h>

// GraphAttention: T=1536 (3 segs of 512), B=8, E=1024, H=16, d=64.
// Round 2: same fp32 pipeline as R1, but d_out is FP32 (reference returns
// float32; R1 wrote bf16 into a float buffer -> decorrelated output, the
// sqrt(2)*max|ref| error signature). qkv fp32 in ws, attn bf16 in ws.

#define T_ALL 1536
#define BSZ 8
#define EMBED 1024
#define HEADS 16
#define HDIM 64
#define SEG 512

using bf16 = __hip_bfloat16;

__device__ inline float bf2f(unsigned short u) {
  return __uint_as_float(((unsigned int)u) << 16);
}
__device__ inline unsigned short f2bf(float f) {
  unsigned int x = __float_as_uint(f);
  x += 0x7fffu + ((x >> 16) & 1u);   // round-to-nearest-even
  return (unsigned short)(x >> 16);
}

__device__ inline void loadA4(const float* p, float o[4]) {
  float4 v = *(const float4*)p;
  o[0] = v.x; o[1] = v.y; o[2] = v.z; o[3] = v.w;
}
__device__ inline void loadA4(const bf16* p, float o[4]) {
  ushort4 v = *(const ushort4*)p;
  o[0] = bf2f(v.x); o[1] = bf2f(v.y); o[2] = bf2f(v.z); o[3] = bf2f(v.w);
}

__device__ inline void store8(float* p, const float* acc, const float* bias) {
  float4 v0, v1;
  v0.x = acc[0] + bias[0]; v0.y = acc[1] + bias[1];
  v0.z = acc[2] + bias[2]; v0.w = acc[3] + bias[3];
  v1.x = acc[4] + bias[4]; v1.y = acc[5] + bias[5];
  v1.z = acc[6] + bias[6]; v1.w = acc[7] + bias[7];
  *(float4*)p = v0;
  *(float4*)(p + 4) = v1;
}
__device__ inline void store8(bf16* p, const float* acc, const float* bias) {
  ushort4 u0, u1;
  u0.x = f2bf(acc[0] + bias[0]); u0.y = f2bf(acc[1] + bias[1]);
  u0.z = f2bf(acc[2] + bias[2]); u0.w = f2bf(acc[3] + bias[3]);
  u1.x = f2bf(acc[4] + bias[4]); u1.y = f2bf(acc[5] + bias[5]);
  u1.z = f2bf(acc[6] + bias[6]); u1.w = f2bf(acc[7] + bias[7]);
  *(ushort4*)p = u0;
  *(ushort4*)(p + 4) = u1;
}

// C[m][n] = sum_k A[m][k] * B[n][k] + bias[n]   (both operands K-contiguous)
// 128x128 tile, 256 threads, 8x8 micro-tile, K-chunk 8.
template <typename TA, typename TC>
__global__ __launch_bounds__(256) void gemm_nt(
    const TA* __restrict__ A, const float* __restrict__ B,
    const float* __restrict__ bias, TC* __restrict__ C,
    int M, int N, int K) {
  __shared__ float As[8][128];
  __shared__ float Bs[8][128];
  const int n0 = blockIdx.x * 128;
  const int m0 = blockIdx.y * 128;
  const int t = threadIdx.x;
  const int tx = t & 15, ty = t >> 4;
  const int lr = t >> 1;            // row within tile 0..127
  const int lk = (t & 1) * 4;       // k offset 0 or 4
  const TA* Ap = A + (size_t)(m0 + lr) * K + lk;
  const float* Bp = B + (size_t)(n0 + lr) * K + lk;

  float acc[8][8];
#pragma unroll
  for (int i = 0; i < 8; ++i)
#pragma unroll
    for (int j = 0; j < 8; ++j) acc[i][j] = 0.f;

  for (int k0 = 0; k0 < K; k0 += 8) {
    float a4[4], b4[4];
    loadA4(Ap + k0, a4);
    loadA4(Bp + k0, b4);
    __syncthreads();  // prev compute done before LDS overwrite
#pragma unroll
    for (int i = 0; i < 4; ++i) {
      As[lk + i][lr] = a4[i];
      Bs[lk + i][lr] = b4[i];
    }
    __syncthreads();
#pragma unroll
    for (int kk = 0; kk < 8; ++kk) {
      float4 av0 = *(const float4*)&As[kk][ty * 8];
      float4 av1 = *(const float4*)&As[kk][ty * 8 + 4];
      float4 bv0 = *(const float4*)&Bs[kk][tx * 8];
      float4 bv1 = *(const float4*)&Bs[kk][tx * 8 + 4];
      float a[8] = {av0.x, av0.y, av0.z, av0.w, av1.x, av1.y, av1.z, av1.w};
      float b[8] = {bv0.x, bv0.y, bv0.z, bv0.w, bv1.x, bv1.y, bv1.z, bv1.w};
#pragma unroll
      for (int i = 0; i < 8; ++i)
#pragma unroll
        for (int j = 0; j < 8; ++j) acc[i][j] += a[i] * b[j];
    }
  }
#pragma unroll
  for (int i = 0; i < 8; ++i) {
    int row = m0 + ty * 8 + i;
    store8(C + (size_t)row * N + n0 + tx * 8, acc[i], bias + n0 + tx * 8);
  }
}

// One block = (bh, pair, 64-row q tile). Online softmax over 8 kv-chunks of 64.
__global__ __launch_bounds__(256) void attn_kernel(
    const float* __restrict__ qkv,  // [T][B][3072]
    bf16* __restrict__ attn) {      // [T][B][1024]
  __shared__ float Qs[64][68];  // [d][q]
  __shared__ float Ks[64][68];  // [d][s]
  __shared__ float Vs[64][68];  // [s][d]
  __shared__ float Ps[64][68];  // [s][q]
  const int qt = blockIdx.x;   // 0..7
  const int pr = blockIdx.y;   // 0..2
  const int bh = blockIdx.z;   // 0..127
  const int b = bh >> 4, h = bh & 15;
  const int t = threadIdx.x;
  const int tx = t & 15, ty = t >> 4;
  const int q_t0 = pr * SEG + qt * 64;
  const int k_t0 = ((pr + 1) % 3) * SEG;

  {  // load Q tile (scaled), store transposed [d][q]
    const int qr = t >> 2;
    const int dc = (t & 3) * 4;
    const float* src =
        qkv + ((size_t)(q_t0 + qr) * BSZ + b) * 3072 + h * HDIM + dc;
#pragma unroll
    for (int i = 0; i < 4; ++i) {
      float4 v = *(const float4*)(src + i * 16);
      int d = dc + i * 16;
      Qs[d + 0][qr] = v.x * 0.125f;
      Qs[d + 1][qr] = v.y * 0.125f;
      Qs[d + 2][qr] = v.z * 0.125f;
      Qs[d + 3][qr] = v.w * 0.125f;
    }
  }

  float m[4], l[4], acc[4][4];
#pragma unroll
  for (int i = 0; i < 4; ++i) {
    m[i] = -1e30f;
    l[i] = 0.f;
#pragma unroll
    for (int j = 0; j < 4; ++j) acc[i][j] = 0.f;
  }

  for (int sc = 0; sc < 8; ++sc) {
    __syncthreads();  // prev PV reads done before K/V overwrite
    {                 // load K chunk (transposed [d][s]) and V chunk ([s][d])
      const int sr = t >> 2;
      const int dc = (t & 3) * 4;
      const float* ksrc = qkv +
          ((size_t)(k_t0 + sc * 64 + sr) * BSZ + b) * 3072 + 1024 + h * HDIM + dc;
      const float* vsrc = ksrc + 1024;
#pragma unroll
      for (int i = 0; i < 4; ++i) {
        int d = dc + i * 16;
        float4 kv4 = *(const float4*)(ksrc + i * 16);
        Ks[d + 0][sr] = kv4.x; Ks[d + 1][sr] = kv4.y;
        Ks[d + 2][sr] = kv4.z; Ks[d + 3][sr] = kv4.w;
        float4 vv4 = *(const float4*)(vsrc + i * 16);
        *(float4*)&Vs[sr][d] = vv4;
      }
    }
    __syncthreads();

    // scores S[4][4]: rows q=ty*4+i, cols s=tx*4+j
    float s4[4][4];
#pragma unroll
    for (int i = 0; i < 4; ++i)
#pragma unroll
      for (int j = 0; j < 4; ++j) s4[i][j] = 0.f;
#pragma unroll 8
    for (int d = 0; d < 64; ++d) {
      float4 qa = *(const float4*)&Qs[d][ty * 4];
      float4 kb = *(const float4*)&Ks[d][tx * 4];
      float a[4] = {qa.x, qa.y, qa.z, qa.w};
      float bb[4] = {kb.x, kb.y, kb.z, kb.w};
#pragma unroll
      for (int i = 0; i < 4; ++i)
#pragma unroll
        for (int j = 0; j < 4; ++j) s4[i][j] += a[i] * bb[j];
    }

    // online softmax update (reduce across the 16 tx-lanes of this ty group)
#pragma unroll
    for (int i = 0; i < 4; ++i) {
      float cm = fmaxf(fmaxf(s4[i][0], s4[i][1]), fmaxf(s4[i][2], s4[i][3]));
      for (int off = 1; off < 16; off <<= 1) cm = fmaxf(cm, __shfl_xor(cm, off));
      float nm = fmaxf(m[i], cm);
      float scale = __expf(m[i] - nm);
      float rs = 0.f;
#pragma unroll
      for (int j = 0; j < 4; ++j) {
        s4[i][j] = __expf(s4[i][j] - nm);
        rs += s4[i][j];
      }
      for (int off = 1; off < 16; off <<= 1) rs += __shfl_xor(rs, off);
      l[i] = l[i] * scale + rs;
      m[i] = nm;
#pragma unroll
      for (int j = 0; j < 4; ++j) acc[i][j] *= scale;
    }

    // P to LDS [s][q]
#pragma unroll
    for (int i = 0; i < 4; ++i)
#pragma unroll
      for (int j = 0; j < 4; ++j) Ps[tx * 4 + j][ty * 4 + i] = s4[i][j];
    __syncthreads();

    // PV: acc[i][j] += sum_s P[q][s] * V[s][dv],  dv = tx*4+j
#pragma unroll 8
    for (int s = 0; s < 64; ++s) {
      float4 pa = *(const float4*)&Ps[s][ty * 4];
      float4 vb = *(const float4*)&Vs[s][tx * 4];
      float a[4] = {pa.x, pa.y, pa.z, pa.w};
      float bb[4] = {vb.x, vb.y, vb.z, vb.w};
#pragma unroll
      for (int i = 0; i < 4; ++i)
#pragma unroll
        for (int j = 0; j < 4; ++j) acc[i][j] += a[i] * bb[j];
    }
  }

  // epilogue: normalize and store bf16
#pragma unroll
  for (int i = 0; i < 4; ++i) {
    float inv = 1.f / l[i];
    ushort4 u;
    u.x = f2bf(acc[i][0] * inv);
    u.y = f2bf(acc[i][1] * inv);
    u.z = f2bf(acc[i][2] * inv);
    u.w = f2bf(acc[i][3] * inv);
    int row = q_t0 + ty * 4 + i;
    *(ushort4*)((unsigned short*)attn +
                ((size_t)row * BSZ + b) * EMBED + h * HDIM + tx * 4) = u;
  }
}

extern "C" void kernel_launch(void* const* d_in, const int* in_sizes, int n_in,
                              void* d_out, int out_size, void* d_ws,
                              size_t ws_size, hipStream_t stream) {
  const float* x     = (const float*)d_in[0];
  const float* w_in  = (const float*)d_in[1];
  const float* b_in  = (const float*)d_in[2];
  const float* w_out = (const float*)d_in[3];
  const float* b_out = (const float*)d_in[4];

  float* qkv = (float*)d_ws;                               // 12288 x 3072 fp32
  bf16* attn = (bf16*)((char*)d_ws + (size_t)12288 * 3072 * 4);  // 12288 x 1024 bf16
  float* out = (float*)d_out;                              // fp32 output!

  dim3 blk(256);
  // QKV projection: [12288 x 1024] @ [3072 x 1024]^T
  gemm_nt<float, float><<<dim3(24, 96), blk, 0, stream>>>(
      x, w_in, b_in, qkv, 12288, 3072, 1024);
  // attention: grid (qtile, pair, b*h)
  attn_kernel<<<dim3(8, 3, 128), blk, 0, stream>>>(qkv, attn);
  // out projection: [12288 x 1024] @ [1024 x 1024]^T -> fp32 d_out
  gemm_nt<bf16, float><<<dim3(8, 96), blk, 0, stream>>>(
      attn, w_out, b_out, out, 12288, 1024, 1024);
}

// Round 3
// 770.144 us; speedup vs baseline: 1.9667x; 1.9667x over previous
//
#include <hip/hip_runtime.h>
#include <hip/hip_bf16.h>

// GraphAttention R3: bf16-MFMA GEMMs with hi/lo split-K precision.
// QKV: [xh|xh|xl] @ [wh|wl|wh]^T, K'=3072 -> qkv bf16.
// attn: R2's fp32 flash kernel, bf16 in, writes attn duplicated [a|a].
// out: [a|a] @ [wh|wl]^T, K'=2048 -> fp32 d_out.

#define T_ALL 1536
#define BSZ 8
#define EMBED 1024
#define HEADS 16
#define HDIM 64
#define SEG 512

using bf16 = __hip_bfloat16;
typedef __attribute__((ext_vector_type(8))) short bf16x8;
typedef __attribute__((ext_vector_type(4))) float f32x4;
typedef __attribute__((ext_vector_type(8))) unsigned short ushort8;

__device__ inline float bf2f(unsigned short u) {
  return __uint_as_float(((unsigned int)u) << 16);
}
__device__ inline unsigned short f2bf(float f) {
  unsigned int x = __float_as_uint(f);
  x += 0x7fffu + ((x >> 16) & 1u);  // RNE
  return (unsigned short)(x >> 16);
}

#define GLOAD_LDS16(g, l)                                      \
  __builtin_amdgcn_global_load_lds(                            \
      (const __attribute__((address_space(1))) void*)(g),      \
      (__attribute__((address_space(3))) void*)(l), 16, 0, 0)

// ---------------- split prep kernels ----------------
// x [12288][1024] f32 -> xs [12288][3072] bf16 = [xh|xh|xl]
__global__ __launch_bounds__(256) void split3_x(const float* __restrict__ x,
                                                unsigned short* __restrict__ xs) {
  int i4 = blockIdx.x * 256 + threadIdx.x;   // 3,145,728 total
  float4 v = *(const float4*)(x + (size_t)i4 * 4);
  int idx = i4 * 4;
  int row = idx >> 10, col = idx & 1023;
  unsigned short* p = xs + (size_t)row * 3072 + col;
  float f[4] = {v.x, v.y, v.z, v.w};
#pragma unroll
  for (int j = 0; j < 4; ++j) {
    unsigned short h = f2bf(f[j]);
    unsigned short l = f2bf(f[j] - bf2f(h));
    p[j] = h; p[1024 + j] = h; p[2048 + j] = l;
  }
}

// w_in [3072][1024] f32 -> ws [3072][3072] bf16 = [wh|wl|wh]
__global__ __launch_bounds__(256) void split3_w(const float* __restrict__ w,
                                                unsigned short* __restrict__ ws) {
  int i4 = blockIdx.x * 256 + threadIdx.x;   // 786,432 total
  float4 v = *(const float4*)(w + (size_t)i4 * 4);
  int idx = i4 * 4;
  int row = idx >> 10, col = idx & 1023;
  unsigned short* p = ws + (size_t)row * 3072 + col;
  float f[4] = {v.x, v.y, v.z, v.w};
#pragma unroll
  for (int j = 0; j < 4; ++j) {
    unsigned short h = f2bf(f[j]);
    unsigned short l = f2bf(f[j] - bf2f(h));
    p[j] = h; p[1024 + j] = l; p[2048 + j] = h;
  }
}

// w_out [1024][1024] f32 -> wos [1024][2048] bf16 = [wh|wl]
__global__ __launch_bounds__(256) void split2_w(const float* __restrict__ w,
                                                unsigned short* __restrict__ ws) {
  int i4 = blockIdx.x * 256 + threadIdx.x;   // 262,144 total
  float4 v = *(const float4*)(w + (size_t)i4 * 4);
  int idx = i4 * 4;
  int row = idx >> 10, col = idx & 1023;
  unsigned short* p = ws + (size_t)row * 2048 + col;
  float f[4] = {v.x, v.y, v.z, v.w};
#pragma unroll
  for (int j = 0; j < 4; ++j) {
    unsigned short h = f2bf(f[j]);
    unsigned short l = f2bf(f[j] - bf2f(h));
    p[j] = h; p[1024 + j] = l;
  }
}

// ---------------- MFMA GEMM (m97 structure) ----------------
// C[m][n] = sum_k A[m][k]*B[n][k] + bias[n]; A,B bf16 K-contig; 128x128 tile,
// BK=32, 4 waves, each wave 64x64 = 4x4 frags of mfma_f32_16x16x32_bf16.
template <typename TC>
__global__ __launch_bounds__(256) void gemm_mfma_nt(
    const unsigned short* __restrict__ A, const unsigned short* __restrict__ B,
    const float* __restrict__ bias, TC* __restrict__ C, int M, int N, int K) {
  __shared__ unsigned short lds_a[128 * 32];
  __shared__ unsigned short lds_b[128 * 32];
  const int t = threadIdx.x;
  const int lane = t & 63, w = t >> 6;
  const int wr = w >> 1, wc = w & 1;
  const int m0 = blockIdx.y * 128, n0 = blockIdx.x * 128;
  const int r16 = lane & 15;   // row within 16-subtile
  const int kb = lane >> 4;    // k-block 0..3 (8 elems each)

  f32x4 acc[4][4];
#pragma unroll
  for (int i = 0; i < 4; ++i)
#pragma unroll
    for (int j = 0; j < 4; ++j) acc[i][j] = f32x4{0.f, 0.f, 0.f, 0.f};

  // staging addresses: chunk c (0..7) covers rows [c*16, c*16+16) of the
  // [128][32] tile; lane l -> row c*16 + l/4, k-elem (l&3)*8.
  const int srow = (lane >> 2), ske = (lane & 3) * 8;

  for (int k0 = 0; k0 < K; k0 += 32) {
    __syncthreads();  // all frag reads of prev tile done
#pragma unroll
    for (int q = 0; q < 2; ++q) {
      int c = q * 4 + w;
      const unsigned short* ga =
          A + (size_t)(m0 + c * 16 + srow) * K + k0 + ske;
      const unsigned short* gb =
          B + (size_t)(n0 + c * 16 + srow) * K + k0 + ske;
      GLOAD_LDS16(ga, &lds_a[c * 512]);
      GLOAD_LDS16(gb, &lds_b[c * 512]);
    }
    __syncthreads();  // drains vmcnt -> LDS tiles ready

    bf16x8 af[4], bfr[4];
#pragma unroll
    for (int i = 0; i < 4; ++i) {
      af[i]  = *(const bf16x8*)&lds_a[(wr * 64 + i * 16 + r16) * 32 + kb * 8];
      bfr[i] = *(const bf16x8*)&lds_b[(wc * 64 + i * 16 + r16) * 32 + kb * 8];
    }
#pragma unroll
    for (int i = 0; i < 4; ++i)
#pragma unroll
      for (int j = 0; j < 4; ++j)
        acc[i][j] = __builtin_amdgcn_mfma_f32_16x16x32_bf16(af[i], bfr[j],
                                                            acc[i][j], 0, 0, 0);
  }

  // epilogue: D col=lane&15, row=(lane>>4)*4+r  [m89 verified layout]
  const int q4 = lane >> 4;
#pragma unroll
  for (int i = 0; i < 4; ++i) {
#pragma unroll
    for (int j = 0; j < 4; ++j) {
      int col = n0 + wc * 64 + j * 16 + r16;
      int rbase = m0 + wr * 64 + i * 16 + q4 * 4;
      float bs = bias[col];
#pragma unroll
      for (int r = 0; r < 4; ++r) {
        float v = acc[i][j][r] + bs;
        if constexpr (sizeof(TC) == 2)
          ((unsigned short*)C)[(size_t)(rbase + r) * N + col] = f2bf(v);
        else
          ((float*)C)[(size_t)(rbase + r) * N + col] = v;
      }
    }
  }
}

// ---------------- attention (fp32 VALU, bf16 qkv in) ----------------
__global__ __launch_bounds__(256) void attn_kernel(
    const unsigned short* __restrict__ qkv,  // [12288][3072] bf16
    unsigned short* __restrict__ attn2) {    // [12288][2048] bf16 = [a|a]
  __shared__ float Qs[64][68];  // [d][q]
  __shared__ float Ks[64][68];  // [d][s]
  __shared__ float Vs[64][68];  // [s][d]
  __shared__ float Ps[64][68];  // [s][q]
  const int qt = blockIdx.x;   // 0..7
  const int pr = blockIdx.y;   // 0..2
  const int bh = blockIdx.z;   // 0..127
  const int b = bh >> 4, h = bh & 15;
  const int t = threadIdx.x;
  const int tx = t & 15, ty = t >> 4;
  const int q_t0 = pr * SEG + qt * 64;
  const int k_t0 = ((pr + 1) % 3) * SEG;

  {  // Q tile -> Qs[d][q], scaled
    const int qr = t >> 2;
    const int dc = (t & 3) * 16;
    const unsigned short* src =
        qkv + ((size_t)(q_t0 + qr) * BSZ + b) * 3072 + h * HDIM + dc;
    ushort8 v0 = *(const ushort8*)src;
    ushort8 v1 = *(const ushort8*)(src + 8);
#pragma unroll
    for (int j = 0; j < 8; ++j) {
      Qs[dc + j][qr] = bf2f(v0[j]) * 0.125f;
      Qs[dc + 8 + j][qr] = bf2f(v1[j]) * 0.125f;
    }
  }

  float m[4], l[4], acc[4][4];
#pragma unroll
  for (int i = 0; i < 4; ++i) {
    m[i] = -1e30f;
    l[i] = 0.f;
#pragma unroll
    for (int j = 0; j < 4; ++j) acc[i][j] = 0.f;
  }

  for (int sc = 0; sc < 8; ++sc) {
    __syncthreads();
    {  // K chunk -> Ks[d][s]; V chunk -> Vs[s][d]
      const int sr = t >> 2;
      const int dc = (t & 3) * 16;
      const unsigned short* ksrc = qkv +
          ((size_t)(k_t0 + sc * 64 + sr) * BSZ + b) * 3072 + 1024 + h * HDIM + dc;
      ushort8 k0 = *(const ushort8*)ksrc;
      ushort8 k1 = *(const ushort8*)(ksrc + 8);
      ushort8 w0 = *(const ushort8*)(ksrc + 1024);
      ushort8 w1 = *(const ushort8*)(ksrc + 1032);
#pragma unroll
      for (int j = 0; j < 8; ++j) {
        Ks[dc + j][sr] = bf2f(k0[j]);
        Ks[dc + 8 + j][sr] = bf2f(k1[j]);
        Vs[sr][dc + j] = bf2f(w0[j]);
        Vs[sr][dc + 8 + j] = bf2f(w1[j]);
      }
    }
    __syncthreads();

    float s4[4][4];
#pragma unroll
    for (int i = 0; i < 4; ++i)
#pragma unroll
      for (int j = 0; j < 4; ++j) s4[i][j] = 0.f;
#pragma unroll 8
    for (int d = 0; d < 64; ++d) {
      float4 qa = *(const float4*)&Qs[d][ty * 4];
      float4 kb = *(const float4*)&Ks[d][tx * 4];
      float a[4] = {qa.x, qa.y, qa.z, qa.w};
      float bb[4] = {kb.x, kb.y, kb.z, kb.w};
#pragma unroll
      for (int i = 0; i < 4; ++i)
#pragma unroll
        for (int j = 0; j < 4; ++j) s4[i][j] += a[i] * bb[j];
    }

#pragma unroll
    for (int i = 0; i < 4; ++i) {
      float cm = fmaxf(fmaxf(s4[i][0], s4[i][1]), fmaxf(s4[i][2], s4[i][3]));
      for (int off = 1; off < 16; off <<= 1) cm = fmaxf(cm, __shfl_xor(cm, off));
      float nm = fmaxf(m[i], cm);
      float scale = __expf(m[i] - nm);
      float rs = 0.f;
#pragma unroll
      for (int j = 0; j < 4; ++j) {
        s4[i][j] = __expf(s4[i][j] - nm);
        rs += s4[i][j];
      }
      for (int off = 1; off < 16; off <<= 1) rs += __shfl_xor(rs, off);
      l[i] = l[i] * scale + rs;
      m[i] = nm;
#pragma unroll
      for (int j = 0; j < 4; ++j) acc[i][j] *= scale;
    }

#pragma unroll
    for (int i = 0; i < 4; ++i)
#pragma unroll
      for (int j = 0; j < 4; ++j) Ps[tx * 4 + j][ty * 4 + i] = s4[i][j];
    __syncthreads();

#pragma unroll 8
    for (int s = 0; s < 64; ++s) {
      float4 pa = *(const float4*)&Ps[s][ty * 4];
      float4 vb = *(const float4*)&Vs[s][tx * 4];
      float a[4] = {pa.x, pa.y, pa.z, pa.w};
      float bb[4] = {vb.x, vb.y, vb.z, vb.w};
#pragma unroll
      for (int i = 0; i < 4; ++i)
#pragma unroll
        for (int j = 0; j < 4; ++j) acc[i][j] += a[i] * bb[j];
    }
  }

#pragma unroll
  for (int i = 0; i < 4; ++i) {
    float inv = 1.f / l[i];
    ushort4 u;
    u.x = f2bf(acc[i][0] * inv);
    u.y = f2bf(acc[i][1] * inv);
    u.z = f2bf(acc[i][2] * inv);
    u.w = f2bf(acc[i][3] * inv);
    int row = q_t0 + ty * 4 + i;
    size_t base = ((size_t)row * BSZ + b) * 2048 + h * HDIM + tx * 4;
    *(ushort4*)(attn2 + base) = u;
    *(ushort4*)(attn2 + base + 1024) = u;   // duplicated for [a|a] layout
  }
}

extern "C" void kernel_launch(void* const* d_in, const int* in_sizes, int n_in,
                              void* d_out, int out_size, void* d_ws,
                              size_t ws_size, hipStream_t stream) {
  const float* x     = (const float*)d_in[0];
  const float* w_in  = (const float*)d_in[1];
  const float* b_in  = (const float*)d_in[2];
  const float* w_out = (const float*)d_in[3];
  const float* b_out = (const float*)d_in[4];

  char* ws = (char*)d_ws;
  // layout (bytes): xs 75.5MB | ws_in 18.9MB | qkv 75.5MB | wos 4.2MB
  // attn2 (50.3MB) aliases xs after the QKV GEMM. total 174.1MB.
  unsigned short* xs    = (unsigned short*)ws;
  unsigned short* ws_in = (unsigned short*)(ws + 75497472ull);
  unsigned short* qkv   = (unsigned short*)(ws + 94371840ull);
  unsigned short* wos   = (unsigned short*)(ws + 169869312ull);
  unsigned short* attn2 = (unsigned short*)ws;  // alias xs (dead after QKV)

  dim3 blk(256);
  split3_x<<<12288, blk, 0, stream>>>(x, xs);
  split3_w<<<3072, blk, 0, stream>>>(w_in, ws_in);
  split2_w<<<1024, blk, 0, stream>>>(w_out, wos);

  // QKV: [12288 x 3072] = xs @ ws_in^T, K'=3072 -> bf16
  gemm_mfma_nt<unsigned short><<<dim3(24, 96), blk, 0, stream>>>(
      xs, ws_in, b_in, qkv, 12288, 3072, 3072);

  attn_kernel<<<dim3(8, 3, 128), blk, 0, stream>>>(qkv, attn2);

  // out: [12288 x 1024] = attn2 @ wos^T, K'=2048 -> fp32
  gemm_mfma_nt<float><<<dim3(8, 96), blk, 0, stream>>>(
      attn2, wos, b_out, (float*)d_out, 12288, 1024, 2048);
}

// Round 4
// 503.978 us; speedup vs baseline: 3.0054x; 1.5281x over previous
//
#include <hip/hip_runtime.h>
#include <hip/hip_bf16.h>

// GraphAttention R4: MFMA attention (flash, bf16 P/V via swizzled LDS).
// QKV GEMM + out GEMM unchanged from R3 (hi/lo split-K bf16 MFMA).

#define T_ALL 1536
#define BSZ 8
#define EMBED 1024
#define HEADS 16
#define HDIM 64
#define SEG 512

using bf16 = __hip_bfloat16;
typedef __attribute__((ext_vector_type(8))) short bf16x8;
typedef __attribute__((ext_vector_type(4))) float f32x4;
typedef __attribute__((ext_vector_type(8))) unsigned short ushort8;

__device__ inline float bf2f(unsigned short u) {
  return __uint_as_float(((unsigned int)u) << 16);
}
__device__ inline unsigned short f2bf(float f) {
  unsigned int x = __float_as_uint(f);
  x += 0x7fffu + ((x >> 16) & 1u);  // RNE
  return (unsigned short)(x >> 16);
}

#define GLOAD_LDS16(g, l)                                      \
  __builtin_amdgcn_global_load_lds(                            \
      (const __attribute__((address_space(1))) void*)(g),      \
      (__attribute__((address_space(3))) void*)(l), 16, 0, 0)

// ---------------- split prep kernels ----------------
__global__ __launch_bounds__(256) void split3_x(const float* __restrict__ x,
                                                unsigned short* __restrict__ xs) {
  int i4 = blockIdx.x * 256 + threadIdx.x;
  float4 v = *(const float4*)(x + (size_t)i4 * 4);
  int idx = i4 * 4;
  int row = idx >> 10, col = idx & 1023;
  unsigned short* p = xs + (size_t)row * 3072 + col;
  float f[4] = {v.x, v.y, v.z, v.w};
#pragma unroll
  for (int j = 0; j < 4; ++j) {
    unsigned short h = f2bf(f[j]);
    unsigned short l = f2bf(f[j] - bf2f(h));
    p[j] = h; p[1024 + j] = h; p[2048 + j] = l;
  }
}

__global__ __launch_bounds__(256) void split3_w(const float* __restrict__ w,
                                                unsigned short* __restrict__ ws) {
  int i4 = blockIdx.x * 256 + threadIdx.x;
  float4 v = *(const float4*)(w + (size_t)i4 * 4);
  int idx = i4 * 4;
  int row = idx >> 10, col = idx & 1023;
  unsigned short* p = ws + (size_t)row * 3072 + col;
  float f[4] = {v.x, v.y, v.z, v.w};
#pragma unroll
  for (int j = 0; j < 4; ++j) {
    unsigned short h = f2bf(f[j]);
    unsigned short l = f2bf(f[j] - bf2f(h));
    p[j] = h; p[1024 + j] = l; p[2048 + j] = h;
  }
}

__global__ __launch_bounds__(256) void split2_w(const float* __restrict__ w,
                                                unsigned short* __restrict__ ws) {
  int i4 = blockIdx.x * 256 + threadIdx.x;
  float4 v = *(const float4*)(w + (size_t)i4 * 4);
  int idx = i4 * 4;
  int row = idx >> 10, col = idx & 1023;
  unsigned short* p = ws + (size_t)row * 2048 + col;
  float f[4] = {v.x, v.y, v.z, v.w};
#pragma unroll
  for (int j = 0; j < 4; ++j) {
    unsigned short h = f2bf(f[j]);
    unsigned short l = f2bf(f[j] - bf2f(h));
    p[j] = h; p[1024 + j] = l;
  }
}

// ---------------- MFMA GEMM (unchanged from R3) ----------------
template <typename TC>
__global__ __launch_bounds__(256) void gemm_mfma_nt(
    const unsigned short* __restrict__ A, const unsigned short* __restrict__ B,
    const float* __restrict__ bias, TC* __restrict__ C, int M, int N, int K) {
  __shared__ unsigned short lds_a[128 * 32];
  __shared__ unsigned short lds_b[128 * 32];
  const int t = threadIdx.x;
  const int lane = t & 63, w = t >> 6;
  const int wr = w >> 1, wc = w & 1;
  const int m0 = blockIdx.y * 128, n0 = blockIdx.x * 128;
  const int r16 = lane & 15;
  const int kb = lane >> 4;

  f32x4 acc[4][4];
#pragma unroll
  for (int i = 0; i < 4; ++i)
#pragma unroll
    for (int j = 0; j < 4; ++j) acc[i][j] = f32x4{0.f, 0.f, 0.f, 0.f};

  const int srow = (lane >> 2), ske = (lane & 3) * 8;

  for (int k0 = 0; k0 < K; k0 += 32) {
    __syncthreads();
#pragma unroll
    for (int q = 0; q < 2; ++q) {
      int c = q * 4 + w;
      const unsigned short* ga =
          A + (size_t)(m0 + c * 16 + srow) * K + k0 + ske;
      const unsigned short* gb =
          B + (size_t)(n0 + c * 16 + srow) * K + k0 + ske;
      GLOAD_LDS16(ga, &lds_a[c * 512]);
      GLOAD_LDS16(gb, &lds_b[c * 512]);
    }
    __syncthreads();

    bf16x8 af[4], bfr[4];
#pragma unroll
    for (int i = 0; i < 4; ++i) {
      af[i]  = *(const bf16x8*)&lds_a[(wr * 64 + i * 16 + r16) * 32 + kb * 8];
      bfr[i] = *(const bf16x8*)&lds_b[(wc * 64 + i * 16 + r16) * 32 + kb * 8];
    }
#pragma unroll
    for (int i = 0; i < 4; ++i)
#pragma unroll
      for (int j = 0; j < 4; ++j)
        acc[i][j] = __builtin_amdgcn_mfma_f32_16x16x32_bf16(af[i], bfr[j],
                                                            acc[i][j], 0, 0, 0);
  }

  const int q4 = lane >> 4;
#pragma unroll
  for (int i = 0; i < 4; ++i) {
#pragma unroll
    for (int j = 0; j < 4; ++j) {
      int col = n0 + wc * 64 + j * 16 + r16;
      int rbase = m0 + wr * 64 + i * 16 + q4 * 4;
      float bs = bias[col];
#pragma unroll
      for (int r = 0; r < 4; ++r) {
        float v = acc[i][j][r] + bs;
        if constexpr (sizeof(TC) == 2)
          ((unsigned short*)C)[(size_t)(rbase + r) * N + col] = f2bf(v);
        else
          ((float*)C)[(size_t)(rbase + r) * N + col] = v;
      }
    }
  }
}

// ---------------- MFMA flash attention ----------------
// Block: 128 q-rows of one (b,h,pair). 4 waves x 32 q-rows (2 x 16-frags).
// 8 kv-chunks of 64. Q,K frags direct from global; P,V^T via swizzled LDS.
__global__ __launch_bounds__(256) void attn_mfma(
    const unsigned short* __restrict__ qkv,  // [12288][3072] bf16
    unsigned short* __restrict__ attn2) {    // [12288][2048] bf16 = [a|a]
  __shared__ unsigned short Vt[64 * 64];     // [d][s] swizzled rows (128 B)
  __shared__ unsigned short Ps[128 * 64];    // [q][s] swizzled rows (128 B)
  const int qt = blockIdx.x;   // 0..3
  const int pr = blockIdx.y;   // 0..2
  const int bh = blockIdx.z;   // 0..127
  const int b = bh >> 4, h = bh & 15;
  const int t = threadIdx.x;
  const int lane = t & 63, w = t >> 6;
  const int r16 = lane & 15;   // frag row / D col
  const int g4 = lane >> 4;    // k-block for A/B frags; row-group for D
  const int q_t0 = pr * SEG + qt * 128;
  const int k_t0 = ((pr + 1) % 3) * SEG;

  // Q fragments (held all kernel), pre-scaled by 1/8 (exact, pow2)
  bf16x8 qf[2][2];
#pragma unroll
  for (int i = 0; i < 2; ++i)
#pragma unroll
    for (int ks = 0; ks < 2; ++ks) {
      const unsigned short* src = qkv +
          ((size_t)(q_t0 + w * 32 + i * 16 + r16) * BSZ + b) * 3072 +
          h * 64 + ks * 32 + g4 * 8;
      ushort8 v = *(const ushort8*)src;
      ushort8 sv;
#pragma unroll
      for (int e = 0; e < 8; ++e) sv[e] = f2bf(bf2f(v[e]) * 0.125f);
      qf[i][ks] = *(bf16x8*)&sv;
    }

  f32x4 acc[2][4];   // O accum, [qfrag][dfrag]
  float mrow[2][4], lrow[2][4];
#pragma unroll
  for (int i = 0; i < 2; ++i) {
#pragma unroll
    for (int j = 0; j < 4; ++j) acc[i][j] = f32x4{0.f, 0.f, 0.f, 0.f};
#pragma unroll
    for (int r = 0; r < 4; ++r) { mrow[i][r] = -3.0e38f; lrow[i][r] = 0.f; }
  }

  for (int sc8 = 0; sc8 < 8; ++sc8) {
    const int s_base = sc8 * 64;

    // K fragments direct from global
    bf16x8 kf[4][2];
#pragma unroll
    for (int j = 0; j < 4; ++j)
#pragma unroll
      for (int ks = 0; ks < 2; ++ks) {
        const unsigned short* src = qkv +
            ((size_t)(k_t0 + s_base + j * 16 + r16) * BSZ + b) * 3072 + 1024 +
            h * 64 + ks * 32 + g4 * 8;
        ushort8 v = *(const ushort8*)src;
        kf[j][ks] = *(bf16x8*)&v;
      }
    // V chunk loads (wave w covers d = w*16 .. w*16+15, lane = s)
    const int vd0 = w * 16;
    const unsigned short* vsrc = qkv +
        ((size_t)(k_t0 + s_base + lane) * BSZ + b) * 3072 + 2048 + h * 64 + vd0;
    ushort8 v0 = *(const ushort8*)vsrc;
    ushort8 v1 = *(const ushort8*)(vsrc + 8);

    // QK^T: s4[i][j] = Q_i . K_j over d=64
    f32x4 s4[2][4];
#pragma unroll
    for (int i = 0; i < 2; ++i)
#pragma unroll
      for (int j = 0; j < 4; ++j) {
        f32x4 a = f32x4{0.f, 0.f, 0.f, 0.f};
        a = __builtin_amdgcn_mfma_f32_16x16x32_bf16(qf[i][0], kf[j][0], a, 0, 0, 0);
        a = __builtin_amdgcn_mfma_f32_16x16x32_bf16(qf[i][1], kf[j][1], a, 0, 0, 0);
        s4[i][j] = a;
      }

    // online softmax: lane holds rows q = i*16 + g4*4 + r, col s = j*16 + r16
#pragma unroll
    for (int i = 0; i < 2; ++i)
#pragma unroll
      for (int r = 0; r < 4; ++r) {
        float cm = fmaxf(fmaxf(s4[i][0][r], s4[i][1][r]),
                         fmaxf(s4[i][2][r], s4[i][3][r]));
        cm = fmaxf(cm, __shfl_xor(cm, 1));
        cm = fmaxf(cm, __shfl_xor(cm, 2));
        cm = fmaxf(cm, __shfl_xor(cm, 4));
        cm = fmaxf(cm, __shfl_xor(cm, 8));
        float nm = fmaxf(mrow[i][r], cm);
        float scale = __expf(mrow[i][r] - nm);
        mrow[i][r] = nm;
        float rs = 0.f;
#pragma unroll
        for (int j = 0; j < 4; ++j) {
          float p = __expf(s4[i][j][r] - nm);
          s4[i][j][r] = p;
          rs += p;
        }
        rs += __shfl_xor(rs, 1);
        rs += __shfl_xor(rs, 2);
        rs += __shfl_xor(rs, 4);
        rs += __shfl_xor(rs, 8);
        lrow[i][r] = lrow[i][r] * scale + rs;
#pragma unroll
        for (int j = 0; j < 4; ++j) acc[i][j][r] *= scale;
      }

    __syncthreads();  // prev chunk's Vt/Ps reads complete

    // stage V^T: Vt[d][s], swizzled byte = d*128 + ((s*2) ^ ((d&7)<<4))
#pragma unroll
    for (int jj = 0; jj < 16; ++jj) {
      int d = vd0 + jj;
      unsigned short val = (jj < 8) ? v0[jj] : v1[jj - 8];
      *(unsigned short*)((char*)Vt + d * 128 + ((lane * 2) ^ ((d & 7) << 4))) = val;
    }
    // write P (bf16, unnormalized): Ps[q][s] swizzled
#pragma unroll
    for (int i = 0; i < 2; ++i)
#pragma unroll
      for (int j = 0; j < 4; ++j)
#pragma unroll
        for (int r = 0; r < 4; ++r) {
          int ql = w * 32 + i * 16 + g4 * 4 + r;
          int sl = j * 16 + r16;
          *(unsigned short*)((char*)Ps + ql * 128 +
                             ((sl * 2) ^ ((ql & 7) << 4))) = f2bf(s4[i][j][r]);
        }
    __syncthreads();  // Vt/Ps ready

    // PV: acc[i][j] += P[q][s] * Vt[d][s]
    bf16x8 pa[2][2], vb[4][2];
#pragma unroll
    for (int i = 0; i < 2; ++i)
#pragma unroll
      for (int ks = 0; ks < 2; ++ks) {
        int ql = w * 32 + i * 16 + r16;
        pa[i][ks] = *(bf16x8*)((char*)Ps + ql * 128 +
                               ((ks * 64 + g4 * 16) ^ ((ql & 7) << 4)));
      }
#pragma unroll
    for (int j = 0; j < 4; ++j)
#pragma unroll
      for (int ks = 0; ks < 2; ++ks) {
        int d = j * 16 + r16;
        vb[j][ks] = *(bf16x8*)((char*)Vt + d * 128 +
                               ((ks * 64 + g4 * 16) ^ ((d & 7) << 4)));
      }
#pragma unroll
    for (int i = 0; i < 2; ++i)
#pragma unroll
      for (int j = 0; j < 4; ++j) {
        acc[i][j] = __builtin_amdgcn_mfma_f32_16x16x32_bf16(pa[i][0], vb[j][0],
                                                            acc[i][j], 0, 0, 0);
        acc[i][j] = __builtin_amdgcn_mfma_f32_16x16x32_bf16(pa[i][1], vb[j][1],
                                                            acc[i][j], 0, 0, 0);
      }
  }

  // epilogue: normalize, store bf16 duplicated [a|a]
#pragma unroll
  for (int i = 0; i < 2; ++i)
#pragma unroll
    for (int r = 0; r < 4; ++r) {
      float inv = 1.f / lrow[i][r];
      int tq = q_t0 + w * 32 + i * 16 + g4 * 4 + r;
      size_t base = ((size_t)tq * BSZ + b) * 2048 + h * 64;
#pragma unroll
      for (int j = 0; j < 4; ++j) {
        unsigned short ob = f2bf(acc[i][j][r] * inv);
        attn2[base + j * 16 + r16] = ob;
        attn2[base + 1024 + j * 16 + r16] = ob;
      }
    }
}

extern "C" void kernel_launch(void* const* d_in, const int* in_sizes, int n_in,
                              void* d_out, int out_size, void* d_ws,
                              size_t ws_size, hipStream_t stream) {
  const float* x     = (const float*)d_in[0];
  const float* w_in  = (const float*)d_in[1];
  const float* b_in  = (const float*)d_in[2];
  const float* w_out = (const float*)d_in[3];
  const float* b_out = (const float*)d_in[4];

  char* ws = (char*)d_ws;
  unsigned short* xs    = (unsigned short*)ws;
  unsigned short* ws_in = (unsigned short*)(ws + 75497472ull);
  unsigned short* qkv   = (unsigned short*)(ws + 94371840ull);
  unsigned short* wos   = (unsigned short*)(ws + 169869312ull);
  unsigned short* attn2 = (unsigned short*)ws;  // alias xs (dead after QKV)

  dim3 blk(256);
  split3_x<<<12288, blk, 0, stream>>>(x, xs);
  split3_w<<<3072, blk, 0, stream>>>(w_in, ws_in);
  split2_w<<<1024, blk, 0, stream>>>(w_out, wos);

  gemm_mfma_nt<unsigned short><<<dim3(24, 96), blk, 0, stream>>>(
      xs, ws_in, b_in, qkv, 12288, 3072, 3072);

  attn_mfma<<<dim3(4, 3, 128), blk, 0, stream>>>(qkv, attn2);

  gemm_mfma_nt<float><<<dim3(8, 96), blk, 0, stream>>>(
      attn2, wos, b_out, (float*)d_out, 12288, 1024, 2048);
}

// Round 5
// 399.416 us; speedup vs baseline: 3.7922x; 1.2618x over previous
//
#include <hip/hip_runtime.h>
#include <hip/hip_bf16.h>

// GraphAttention R5: QKV split reduced 3->2 terms: [xh|xh] @ [wh|wl]^T,
// K'=2048 (= xh.w, dropping xl.w ~ 2^-9 rel on x; predicted +<1e-3 absmax).
// MFMA GEMM + MFMA attention unchanged from R4.

#define T_ALL 1536
#define BSZ 8
#define EMBED 1024
#define HEADS 16
#define HDIM 64
#define SEG 512

using bf16 = __hip_bfloat16;
typedef __attribute__((ext_vector_type(8))) short bf16x8;
typedef __attribute__((ext_vector_type(4))) float f32x4;
typedef __attribute__((ext_vector_type(8))) unsigned short ushort8;

__device__ inline float bf2f(unsigned short u) {
  return __uint_as_float(((unsigned int)u) << 16);
}
__device__ inline unsigned short f2bf(float f) {
  unsigned int x = __float_as_uint(f);
  x += 0x7fffu + ((x >> 16) & 1u);  // RNE
  return (unsigned short)(x >> 16);
}

#define GLOAD_LDS16(g, l)                                      \
  __builtin_amdgcn_global_load_lds(                            \
      (const __attribute__((address_space(1))) void*)(g),      \
      (__attribute__((address_space(3))) void*)(l), 16, 0, 0)

// ---------------- split prep kernels ----------------
// x [12288][1024] f32 -> xs [12288][2048] bf16 = [xh|xh]
__global__ __launch_bounds__(256) void splitdup_x(const float* __restrict__ x,
                                                  unsigned short* __restrict__ xs) {
  int i4 = blockIdx.x * 256 + threadIdx.x;
  float4 v = *(const float4*)(x + (size_t)i4 * 4);
  int idx = i4 * 4;
  int row = idx >> 10, col = idx & 1023;
  unsigned short* p = xs + (size_t)row * 2048 + col;
  float f[4] = {v.x, v.y, v.z, v.w};
#pragma unroll
  for (int j = 0; j < 4; ++j) {
    unsigned short h = f2bf(f[j]);
    p[j] = h; p[1024 + j] = h;
  }
}

// w [R][1024] f32 -> ws [R][2048] bf16 = [wh|wl]  (grid = R blocks)
__global__ __launch_bounds__(256) void split2_w(const float* __restrict__ w,
                                                unsigned short* __restrict__ ws) {
  int i4 = blockIdx.x * 256 + threadIdx.x;
  float4 v = *(const float4*)(w + (size_t)i4 * 4);
  int idx = i4 * 4;
  int row = idx >> 10, col = idx & 1023;
  unsigned short* p = ws + (size_t)row * 2048 + col;
  float f[4] = {v.x, v.y, v.z, v.w};
#pragma unroll
  for (int j = 0; j < 4; ++j) {
    unsigned short h = f2bf(f[j]);
    unsigned short l = f2bf(f[j] - bf2f(h));
    p[j] = h; p[1024 + j] = l;
  }
}

// ---------------- MFMA GEMM (unchanged from R4) ----------------
template <typename TC>
__global__ __launch_bounds__(256) void gemm_mfma_nt(
    const unsigned short* __restrict__ A, const unsigned short* __restrict__ B,
    const float* __restrict__ bias, TC* __restrict__ C, int M, int N, int K) {
  __shared__ unsigned short lds_a[128 * 32];
  __shared__ unsigned short lds_b[128 * 32];
  const int t = threadIdx.x;
  const int lane = t & 63, w = t >> 6;
  const int wr = w >> 1, wc = w & 1;
  const int m0 = blockIdx.y * 128, n0 = blockIdx.x * 128;
  const int r16 = lane & 15;
  const int kb = lane >> 4;

  f32x4 acc[4][4];
#pragma unroll
  for (int i = 0; i < 4; ++i)
#pragma unroll
    for (int j = 0; j < 4; ++j) acc[i][j] = f32x4{0.f, 0.f, 0.f, 0.f};

  const int srow = (lane >> 2), ske = (lane & 3) * 8;

  for (int k0 = 0; k0 < K; k0 += 32) {
    __syncthreads();
#pragma unroll
    for (int q = 0; q < 2; ++q) {
      int c = q * 4 + w;
      const unsigned short* ga =
          A + (size_t)(m0 + c * 16 + srow) * K + k0 + ske;
      const unsigned short* gb =
          B + (size_t)(n0 + c * 16 + srow) * K + k0 + ske;
      GLOAD_LDS16(ga, &lds_a[c * 512]);
      GLOAD_LDS16(gb, &lds_b[c * 512]);
    }
    __syncthreads();

    bf16x8 af[4], bfr[4];
#pragma unroll
    for (int i = 0; i < 4; ++i) {
      af[i]  = *(const bf16x8*)&lds_a[(wr * 64 + i * 16 + r16) * 32 + kb * 8];
      bfr[i] = *(const bf16x8*)&lds_b[(wc * 64 + i * 16 + r16) * 32 + kb * 8];
    }
#pragma unroll
    for (int i = 0; i < 4; ++i)
#pragma unroll
      for (int j = 0; j < 4; ++j)
        acc[i][j] = __builtin_amdgcn_mfma_f32_16x16x32_bf16(af[i], bfr[j],
                                                            acc[i][j], 0, 0, 0);
  }

  const int q4 = lane >> 4;
#pragma unroll
  for (int i = 0; i < 4; ++i) {
#pragma unroll
    for (int j = 0; j < 4; ++j) {
      int col = n0 + wc * 64 + j * 16 + r16;
      int rbase = m0 + wr * 64 + i * 16 + q4 * 4;
      float bs = bias[col];
#pragma unroll
      for (int r = 0; r < 4; ++r) {
        float v = acc[i][j][r] + bs;
        if constexpr (sizeof(TC) == 2)
          ((unsigned short*)C)[(size_t)(rbase + r) * N + col] = f2bf(v);
        else
          ((float*)C)[(size_t)(rbase + r) * N + col] = v;
      }
    }
  }
}

// ---------------- MFMA flash attention (unchanged from R4) ----------------
__global__ __launch_bounds__(256) void attn_mfma(
    const unsigned short* __restrict__ qkv,  // [12288][3072] bf16
    unsigned short* __restrict__ attn2) {    // [12288][2048] bf16 = [a|a]
  __shared__ unsigned short Vt[64 * 64];
  __shared__ unsigned short Ps[128 * 64];
  const int qt = blockIdx.x;
  const int pr = blockIdx.y;
  const int bh = blockIdx.z;
  const int b = bh >> 4, h = bh & 15;
  const int t = threadIdx.x;
  const int lane = t & 63, w = t >> 6;
  const int r16 = lane & 15;
  const int g4 = lane >> 4;
  const int q_t0 = pr * SEG + qt * 128;
  const int k_t0 = ((pr + 1) % 3) * SEG;

  bf16x8 qf[2][2];
#pragma unroll
  for (int i = 0; i < 2; ++i)
#pragma unroll
    for (int ks = 0; ks < 2; ++ks) {
      const unsigned short* src = qkv +
          ((size_t)(q_t0 + w * 32 + i * 16 + r16) * BSZ + b) * 3072 +
          h * 64 + ks * 32 + g4 * 8;
      ushort8 v = *(const ushort8*)src;
      ushort8 sv;
#pragma unroll
      for (int e = 0; e < 8; ++e) sv[e] = f2bf(bf2f(v[e]) * 0.125f);
      qf[i][ks] = *(bf16x8*)&sv;
    }

  f32x4 acc[2][4];
  float mrow[2][4], lrow[2][4];
#pragma unroll
  for (int i = 0; i < 2; ++i) {
#pragma unroll
    for (int j = 0; j < 4; ++j) acc[i][j] = f32x4{0.f, 0.f, 0.f, 0.f};
#pragma unroll
    for (int r = 0; r < 4; ++r) { mrow[i][r] = -3.0e38f; lrow[i][r] = 0.f; }
  }

  for (int sc8 = 0; sc8 < 8; ++sc8) {
    const int s_base = sc8 * 64;

    bf16x8 kf[4][2];
#pragma unroll
    for (int j = 0; j < 4; ++j)
#pragma unroll
      for (int ks = 0; ks < 2; ++ks) {
        const unsigned short* src = qkv +
            ((size_t)(k_t0 + s_base + j * 16 + r16) * BSZ + b) * 3072 + 1024 +
            h * 64 + ks * 32 + g4 * 8;
        ushort8 v = *(const ushort8*)src;
        kf[j][ks] = *(bf16x8*)&v;
      }
    const int vd0 = w * 16;
    const unsigned short* vsrc = qkv +
        ((size_t)(k_t0 + s_base + lane) * BSZ + b) * 3072 + 2048 + h * 64 + vd0;
    ushort8 v0 = *(const ushort8*)vsrc;
    ushort8 v1 = *(const ushort8*)(vsrc + 8);

    f32x4 s4[2][4];
#pragma unroll
    for (int i = 0; i < 2; ++i)
#pragma unroll
      for (int j = 0; j < 4; ++j) {
        f32x4 a = f32x4{0.f, 0.f, 0.f, 0.f};
        a = __builtin_amdgcn_mfma_f32_16x16x32_bf16(qf[i][0], kf[j][0], a, 0, 0, 0);
        a = __builtin_amdgcn_mfma_f32_16x16x32_bf16(qf[i][1], kf[j][1], a, 0, 0, 0);
        s4[i][j] = a;
      }

#pragma unroll
    for (int i = 0; i < 2; ++i)
#pragma unroll
      for (int r = 0; r < 4; ++r) {
        float cm = fmaxf(fmaxf(s4[i][0][r], s4[i][1][r]),
                         fmaxf(s4[i][2][r], s4[i][3][r]));
        cm = fmaxf(cm, __shfl_xor(cm, 1));
        cm = fmaxf(cm, __shfl_xor(cm, 2));
        cm = fmaxf(cm, __shfl_xor(cm, 4));
        cm = fmaxf(cm, __shfl_xor(cm, 8));
        float nm = fmaxf(mrow[i][r], cm);
        float scale = __expf(mrow[i][r] - nm);
        mrow[i][r] = nm;
        float rs = 0.f;
#pragma unroll
        for (int j = 0; j < 4; ++j) {
          float p = __expf(s4[i][j][r] - nm);
          s4[i][j][r] = p;
          rs += p;
        }
        rs += __shfl_xor(rs, 1);
        rs += __shfl_xor(rs, 2);
        rs += __shfl_xor(rs, 4);
        rs += __shfl_xor(rs, 8);
        lrow[i][r] = lrow[i][r] * scale + rs;
#pragma unroll
        for (int j = 0; j < 4; ++j) acc[i][j][r] *= scale;
      }

    __syncthreads();

#pragma unroll
    for (int jj = 0; jj < 16; ++jj) {
      int d = vd0 + jj;
      unsigned short val = (jj < 8) ? v0[jj] : v1[jj - 8];
      *(unsigned short*)((char*)Vt + d * 128 + ((lane * 2) ^ ((d & 7) << 4))) = val;
    }
#pragma unroll
    for (int i = 0; i < 2; ++i)
#pragma unroll
      for (int j = 0; j < 4; ++j)
#pragma unroll
        for (int r = 0; r < 4; ++r) {
          int ql = w * 32 + i * 16 + g4 * 4 + r;
          int sl = j * 16 + r16;
          *(unsigned short*)((char*)Ps + ql * 128 +
                             ((sl * 2) ^ ((ql & 7) << 4))) = f2bf(s4[i][j][r]);
        }
    __syncthreads();

    bf16x8 pa[2][2], vb[4][2];
#pragma unroll
    for (int i = 0; i < 2; ++i)
#pragma unroll
      for (int ks = 0; ks < 2; ++ks) {
        int ql = w * 32 + i * 16 + r16;
        pa[i][ks] = *(bf16x8*)((char*)Ps + ql * 128 +
                               ((ks * 64 + g4 * 16) ^ ((ql & 7) << 4)));
      }
#pragma unroll
    for (int j = 0; j < 4; ++j)
#pragma unroll
      for (int ks = 0; ks < 2; ++ks) {
        int d = j * 16 + r16;
        vb[j][ks] = *(bf16x8*)((char*)Vt + d * 128 +
                               ((ks * 64 + g4 * 16) ^ ((d & 7) << 4)));
      }
#pragma unroll
    for (int i = 0; i < 2; ++i)
#pragma unroll
      for (int j = 0; j < 4; ++j) {
        acc[i][j] = __builtin_amdgcn_mfma_f32_16x16x32_bf16(pa[i][0], vb[j][0],
                                                            acc[i][j], 0, 0, 0);
        acc[i][j] = __builtin_amdgcn_mfma_f32_16x16x32_bf16(pa[i][1], vb[j][1],
                                                            acc[i][j], 0, 0, 0);
      }
  }

#pragma unroll
  for (int i = 0; i < 2; ++i)
#pragma unroll
    for (int r = 0; r < 4; ++r) {
      float inv = 1.f / lrow[i][r];
      int tq = q_t0 + w * 32 + i * 16 + g4 * 4 + r;
      size_t base = ((size_t)tq * BSZ + b) * 2048 + h * 64;
#pragma unroll
      for (int j = 0; j < 4; ++j) {
        unsigned short ob = f2bf(acc[i][j][r] * inv);
        attn2[base + j * 16 + r16] = ob;
        attn2[base + 1024 + j * 16 + r16] = ob;
      }
    }
}

extern "C" void kernel_launch(void* const* d_in, const int* in_sizes, int n_in,
                              void* d_out, int out_size, void* d_ws,
                              size_t ws_size, hipStream_t stream) {
  const float* x     = (const float*)d_in[0];
  const float* w_in  = (const float*)d_in[1];
  const float* b_in  = (const float*)d_in[2];
  const float* w_out = (const float*)d_in[3];
  const float* b_out = (const float*)d_in[4];

  char* ws = (char*)d_ws;
  // layout: xs 50.3MB | ws_in 12.6MB | qkv 75.5MB | wos 4.2MB  (142.6MB)
  unsigned short* xs    = (unsigned short*)ws;
  unsigned short* ws_in = (unsigned short*)(ws + 50331648ull);
  unsigned short* qkv   = (unsigned short*)(ws + 62914560ull);
  unsigned short* wos   = (unsigned short*)(ws + 138412032ull);
  unsigned short* attn2 = (unsigned short*)ws;  // alias xs (dead after QKV)

  dim3 blk(256);
  splitdup_x<<<12288, blk, 0, stream>>>(x, xs);
  split2_w<<<3072, blk, 0, stream>>>(w_in, ws_in);   // [wh|wl] for w_in
  split2_w<<<1024, blk, 0, stream>>>(w_out, wos);    // [wh|wl] for w_out

  // QKV: [12288 x 3072] = [xh|xh] @ [wh|wl]^T, K'=2048 -> bf16
  gemm_mfma_nt<unsigned short><<<dim3(24, 96), blk, 0, stream>>>(
      xs, ws_in, b_in, qkv, 12288, 3072, 2048);

  attn_mfma<<<dim3(4, 3, 128), blk, 0, stream>>>(qkv, attn2);

  // out: [12288 x 1024] = [a|a] @ [wh|wl]^T, K'=2048 -> fp32
  gemm_mfma_nt<float><<<dim3(8, 96), blk, 0, stream>>>(
      attn2, wos, b_out, (float*)d_out, 12288, 1024, 2048);
}

// Round 6
// 366.504 us; speedup vs baseline: 4.1327x; 1.0898x over previous
//
#include <hip/hip_runtime.h>
#include <hip/hip_bf16.h>

// GraphAttention R6: 256x256 8-phase deep-pipelined MFMA GEMM (T2+T3+T4+T5)
// for QKV and out-proj. Counted vmcnt(4) at tile boundaries (never 0 in
// steady state), raw s_barrier, setprio around MFMA, XOR-swizzled LDS with
// pre-swizzled global_load_lds source. Attention + split preps = R5.

#define T_ALL 1536
#define BSZ 8
#define EMBED 1024
#define HEADS 16
#define HDIM 64
#define SEG 512

using bf16 = __hip_bfloat16;
using ushort = unsigned short;
typedef __attribute__((ext_vector_type(8))) short bf16x8;
typedef __attribute__((ext_vector_type(4))) float f32x4;
typedef __attribute__((ext_vector_type(8))) unsigned short ushort8;

__device__ inline float bf2f(ushort u) {
  return __uint_as_float(((unsigned int)u) << 16);
}
__device__ inline ushort f2bf(float f) {
  unsigned int x = __float_as_uint(f);
  x += 0x7fffu + ((x >> 16) & 1u);  // RNE
  return (ushort)(x >> 16);
}

#define GLOAD_LDS16(g, l)                                      \
  __builtin_amdgcn_global_load_lds(                            \
      (const __attribute__((address_space(1))) void*)(g),      \
      (__attribute__((address_space(3))) void*)(l), 16, 0, 0)

// ---------------- split prep kernels (unchanged) ----------------
__global__ __launch_bounds__(256) void splitdup_x(const float* __restrict__ x,
                                                  ushort* __restrict__ xs) {
  int i4 = blockIdx.x * 256 + threadIdx.x;
  float4 v = *(const float4*)(x + (size_t)i4 * 4);
  int idx = i4 * 4;
  int row = idx >> 10, col = idx & 1023;
  ushort* p = xs + (size_t)row * 2048 + col;
  float f[4] = {v.x, v.y, v.z, v.w};
#pragma unroll
  for (int j = 0; j < 4; ++j) {
    ushort h = f2bf(f[j]);
    p[j] = h; p[1024 + j] = h;
  }
}

__global__ __launch_bounds__(256) void split2_w(const float* __restrict__ w,
                                                ushort* __restrict__ ws) {
  int i4 = blockIdx.x * 256 + threadIdx.x;
  float4 v = *(const float4*)(w + (size_t)i4 * 4);
  int idx = i4 * 4;
  int row = idx >> 10, col = idx & 1023;
  ushort* p = ws + (size_t)row * 2048 + col;
  float f[4] = {v.x, v.y, v.z, v.w};
#pragma unroll
  for (int j = 0; j < 4; ++j) {
    ushort h = f2bf(f[j]);
    ushort l = f2bf(f[j] - bf2f(h));
    p[j] = h; p[1024 + j] = l;
  }
}

// ---------------- 256^2 8-phase MFMA GEMM ----------------
#define BAR_LGKM()                                     \
  __builtin_amdgcn_s_barrier();                        \
  asm volatile("s_waitcnt lgkmcnt(0)" ::: "memory");   \
  __builtin_amdgcn_sched_barrier(0);

#define QUAD(IBASE, JBASE, BF)                                             \
  __builtin_amdgcn_s_setprio(1);                                           \
  _Pragma("unroll")                                                        \
  for (int i = 0; i < 4; ++i) {                                            \
    _Pragma("unroll")                                                      \
    for (int j = 0; j < 2; ++j) {                                          \
      acc[IBASE + i][JBASE + j] = __builtin_amdgcn_mfma_f32_16x16x32_bf16( \
          af[i][0], BF[j][0], acc[IBASE + i][JBASE + j], 0, 0, 0);         \
      acc[IBASE + i][JBASE + j] = __builtin_amdgcn_mfma_f32_16x16x32_bf16( \
          af[i][1], BF[j][1], acc[IBASE + i][JBASE + j], 0, 0, 0);         \
    }                                                                      \
  }                                                                        \
  __builtin_amdgcn_s_setprio(0);

template <typename TC>
__global__ __launch_bounds__(512, 2) void gemm8_nt(
    const ushort* __restrict__ A, const ushort* __restrict__ B,
    const float* __restrict__ bias, TC* __restrict__ C,
    int N, int K, int nN) {
  __shared__ char lds[131072];  // [buf][mat][256 rows * 128 B]
  const int tid = threadIdx.x;
  const int lane = tid & 63, wid = tid >> 6;
  const int wr = wid >> 2, wcn = wid & 3;
  const int r16 = lane & 15, g4 = lane >> 4;

  const int nwg = gridDim.x;
  const int bid = blockIdx.x;
  const int swz = (bid & 7) * (nwg >> 3) + (bid >> 3);
  const int m0 = (swz / nN) * 256, n0 = (swz % nN) * 256;

  const int NT = K >> 6;

  auto STAGE = [&](const ushort* G, int gr0, int ldso, int half, int kcol) {
#pragma unroll
    for (int q = 0; q < 2; ++q) {
      int row = half * 128 + q * 64 + (tid >> 3);
      int sl = (tid & 7) ^ (row & 7);
      const ushort* src = G + (size_t)(gr0 + row) * K + kcol + sl * 8;
      GLOAD_LDS16(src, lds + ldso + row * 128 + (tid & 7) * 16);
    }
  };
  auto LD = [&](int ldso, int row, int kk) -> bf16x8 {
    return *(const bf16x8*)(lds + ldso + row * 128 +
                            ((kk * 64 + g4 * 16) ^ ((row & 7) << 4)));
  };

  f32x4 acc[8][4];
#pragma unroll
  for (int i = 0; i < 8; ++i)
#pragma unroll
    for (int j = 0; j < 4; ++j) acc[i][j] = f32x4{0.f, 0.f, 0.f, 0.f};

  STAGE(A, m0, 0,      0, 0);
  STAGE(B, n0, 32768,  0, 0);
  STAGE(A, m0, 0,      1, 0);
  STAGE(B, n0, 32768,  1, 0);
  if (NT > 1) {
    STAGE(A, m0, 65536, 0, 64);
    STAGE(B, n0, 98304, 0, 64);
    asm volatile("s_waitcnt vmcnt(4)" ::: "memory");
  } else {
    asm volatile("s_waitcnt vmcnt(0)" ::: "memory");
  }
  __builtin_amdgcn_s_barrier();

  bf16x8 af[4][2], bfA[2][2], bfB[2][2];
  int cur = 0;
  for (int t = 0; t < NT; ++t) {
    const int aC = cur * 65536, bC = aC + 32768;
    const int aN = (cur ^ 1) * 65536, bN = aN + 32768;
    // ---- p0
#pragma unroll
    for (int i = 0; i < 4; ++i) {
      int ar = wr * 64 + i * 16 + r16;
      af[i][0] = LD(aC, ar, 0);
      af[i][1] = LD(aC, ar, 1);
    }
#pragma unroll
    for (int j = 0; j < 2; ++j) {
      int br = wcn * 32 + j * 16 + r16;
      bfA[j][0] = LD(bC, br, 0);
      bfA[j][1] = LD(bC, br, 1);
    }
    if (t + 1 < NT) STAGE(A, m0, aN, 1, (t + 1) * 64);
    BAR_LGKM();
    QUAD(0, 0, bfA);
    __builtin_amdgcn_s_barrier();
    // ---- p1
#pragma unroll
    for (int j = 0; j < 2; ++j) {
      int br = wcn * 32 + 128 + j * 16 + r16;
      bfB[j][0] = LD(bC, br, 0);
      bfB[j][1] = LD(bC, br, 1);
    }
    if (t + 1 < NT) STAGE(B, n0, bN, 1, (t + 1) * 64);
    BAR_LGKM();
    QUAD(0, 2, bfB);
    __builtin_amdgcn_s_barrier();
    // ---- p2
#pragma unroll
    for (int i = 0; i < 4; ++i) {
      int ar = wr * 64 + 128 + i * 16 + r16;
      af[i][0] = LD(aC, ar, 0);
      af[i][1] = LD(aC, ar, 1);
    }
    if (t + 2 < NT) STAGE(A, m0, aC, 0, (t + 2) * 64);
    BAR_LGKM();
    QUAD(4, 0, bfA);
    __builtin_amdgcn_s_barrier();
    // ---- p3
    if (t + 2 < NT) {
      STAGE(B, n0, bC, 0, (t + 2) * 64);
      asm volatile("s_waitcnt vmcnt(4)" ::: "memory");
    } else {
      asm volatile("s_waitcnt vmcnt(0)" ::: "memory");
    }
    __builtin_amdgcn_s_barrier();
    QUAD(4, 2, bfB);
    __builtin_amdgcn_s_barrier();
    cur ^= 1;
  }

#pragma unroll
  for (int i = 0; i < 8; ++i) {
    int row = m0 + wr * 64 + (i >> 2) * 128 + (i & 3) * 16 + g4 * 4;
#pragma unroll
    for (int j = 0; j < 4; ++j) {
      int col = n0 + wcn * 32 + (j >> 1) * 128 + (j & 1) * 16 + r16;
      float bs = bias[col];
#pragma unroll
      for (int r = 0; r < 4; ++r) {
        float v = acc[i][j][r] + bs;
        if constexpr (sizeof(TC) == 2)
          ((ushort*)C)[(size_t)(row + r) * N + col] = f2bf(v);
        else
          ((float*)C)[(size_t)(row + r) * N + col] = v;
      }
    }
  }
}

// ---------------- MFMA flash attention (unchanged from R4/R5) ----------------
__global__ __launch_bounds__(256) void attn_mfma(
    const ushort* __restrict__ qkv,
    ushort* __restrict__ attn2) {
  __shared__ ushort Vt[64 * 64];
  __shared__ ushort Ps[128 * 64];
  const int qt = blockIdx.x;
  const int pr = blockIdx.y;
  const int bh = blockIdx.z;
  const int b = bh >> 4, h = bh & 15;
  const int t = threadIdx.x;
  const int lane = t & 63, w = t >> 6;
  const int r16 = lane & 15;
  const int g4 = lane >> 4;
  const int q_t0 = pr * SEG + qt * 128;
  const int k_t0 = ((pr + 1) % 3) * SEG;

  bf16x8 qf[2][2];
#pragma unroll
  for (int i = 0; i < 2; ++i)
#pragma unroll
    for (int ks = 0; ks < 2; ++ks) {
      const ushort* src = qkv +
          ((size_t)(q_t0 + w * 32 + i * 16 + r16) * BSZ + b) * 3072 +
          h * 64 + ks * 32 + g4 * 8;
      ushort8 v = *(const ushort8*)src;
      ushort8 sv;
#pragma unroll
      for (int e = 0; e < 8; ++e) sv[e] = f2bf(bf2f(v[e]) * 0.125f);
      qf[i][ks] = *(bf16x8*)&sv;
    }

  f32x4 acc[2][4];
  float mrow[2][4], lrow[2][4];
#pragma unroll
  for (int i = 0; i < 2; ++i) {
#pragma unroll
    for (int j = 0; j < 4; ++j) acc[i][j] = f32x4{0.f, 0.f, 0.f, 0.f};
#pragma unroll
    for (int r = 0; r < 4; ++r) { mrow[i][r] = -3.0e38f; lrow[i][r] = 0.f; }
  }

  for (int sc8 = 0; sc8 < 8; ++sc8) {
    const int s_base = sc8 * 64;

    bf16x8 kf[4][2];
#pragma unroll
    for (int j = 0; j < 4; ++j)
#pragma unroll
      for (int ks = 0; ks < 2; ++ks) {
        const ushort* src = qkv +
            ((size_t)(k_t0 + s_base + j * 16 + r16) * BSZ + b) * 3072 + 1024 +
            h * 64 + ks * 32 + g4 * 8;
        ushort8 v = *(const ushort8*)src;
        kf[j][ks] = *(bf16x8*)&v;
      }
    const int vd0 = w * 16;
    const ushort* vsrc = qkv +
        ((size_t)(k_t0 + s_base + lane) * BSZ + b) * 3072 + 2048 + h * 64 + vd0;
    ushort8 v0 = *(const ushort8*)vsrc;
    ushort8 v1 = *(const ushort8*)(vsrc + 8);

    f32x4 s4[2][4];
#pragma unroll
    for (int i = 0; i < 2; ++i)
#pragma unroll
      for (int j = 0; j < 4; ++j) {
        f32x4 a = f32x4{0.f, 0.f, 0.f, 0.f};
        a = __builtin_amdgcn_mfma_f32_16x16x32_bf16(qf[i][0], kf[j][0], a, 0, 0, 0);
        a = __builtin_amdgcn_mfma_f32_16x16x32_bf16(qf[i][1], kf[j][1], a, 0, 0, 0);
        s4[i][j] = a;
      }

#pragma unroll
    for (int i = 0; i < 2; ++i)
#pragma unroll
      for (int r = 0; r < 4; ++r) {
        float cm = fmaxf(fmaxf(s4[i][0][r], s4[i][1][r]),
                         fmaxf(s4[i][2][r], s4[i][3][r]));
        cm = fmaxf(cm, __shfl_xor(cm, 1));
        cm = fmaxf(cm, __shfl_xor(cm, 2));
        cm = fmaxf(cm, __shfl_xor(cm, 4));
        cm = fmaxf(cm, __shfl_xor(cm, 8));
        float nm = fmaxf(mrow[i][r], cm);
        float scale = __expf(mrow[i][r] - nm);
        mrow[i][r] = nm;
        float rs = 0.f;
#pragma unroll
        for (int j = 0; j < 4; ++j) {
          float p = __expf(s4[i][j][r] - nm);
          s4[i][j][r] = p;
          rs += p;
        }
        rs += __shfl_xor(rs, 1);
        rs += __shfl_xor(rs, 2);
        rs += __shfl_xor(rs, 4);
        rs += __shfl_xor(rs, 8);
        lrow[i][r] = lrow[i][r] * scale + rs;
#pragma unroll
        for (int j = 0; j < 4; ++j) acc[i][j][r] *= scale;
      }

    __syncthreads();

#pragma unroll
    for (int jj = 0; jj < 16; ++jj) {
      int d = vd0 + jj;
      ushort val = (jj < 8) ? v0[jj] : v1[jj - 8];
      *(ushort*)((char*)Vt + d * 128 + ((lane * 2) ^ ((d & 7) << 4))) = val;
    }
#pragma unroll
    for (int i = 0; i < 2; ++i)
#pragma unroll
      for (int j = 0; j < 4; ++j)
#pragma unroll
        for (int r = 0; r < 4; ++r) {
          int ql = w * 32 + i * 16 + g4 * 4 + r;
          int sl = j * 16 + r16;
          *(ushort*)((char*)Ps + ql * 128 +
                     ((sl * 2) ^ ((ql & 7) << 4))) = f2bf(s4[i][j][r]);
        }
    __syncthreads();

    bf16x8 pa[2][2], vb[4][2];
#pragma unroll
    for (int i = 0; i < 2; ++i)
#pragma unroll
      for (int ks = 0; ks < 2; ++ks) {
        int ql = w * 32 + i * 16 + r16;
        pa[i][ks] = *(bf16x8*)((char*)Ps + ql * 128 +
                               ((ks * 64 + g4 * 16) ^ ((ql & 7) << 4)));
      }
#pragma unroll
    for (int j = 0; j < 4; ++j)
#pragma unroll
      for (int ks = 0; ks < 2; ++ks) {
        int d = j * 16 + r16;
        vb[j][ks] = *(bf16x8*)((char*)Vt + d * 128 +
                               ((ks * 64 + g4 * 16) ^ ((d & 7) << 4)));
      }
#pragma unroll
    for (int i = 0; i < 2; ++i)
#pragma unroll
      for (int j = 0; j < 4; ++j) {
        acc[i][j] = __builtin_amdgcn_mfma_f32_16x16x32_bf16(pa[i][0], vb[j][0],
                                                            acc[i][j], 0, 0, 0);
        acc[i][j] = __builtin_amdgcn_mfma_f32_16x16x32_bf16(pa[i][1], vb[j][1],
                                                            acc[i][j], 0, 0, 0);
      }
  }

#pragma unroll
  for (int i = 0; i < 2; ++i)
#pragma unroll
    for (int r = 0; r < 4; ++r) {
      float inv = 1.f / lrow[i][r];
      int tq = q_t0 + w * 32 + i * 16 + g4 * 4 + r;
      size_t base = ((size_t)tq * BSZ + b) * 2048 + h * 64;
#pragma unroll
      for (int j = 0; j < 4; ++j) {
        ushort ob = f2bf(acc[i][j][r] * inv);
        attn2[base + j * 16 + r16] = ob;
        attn2[base + 1024 + j * 16 + r16] = ob;
      }
    }
}

extern "C" void kernel_launch(void* const* d_in, const int* in_sizes, int n_in,
                              void* d_out, int out_size, void* d_ws,
                              size_t ws_size, hipStream_t stream) {
  const float* x     = (const float*)d_in[0];
  const float* w_in  = (const float*)d_in[1];
  const float* b_in  = (const float*)d_in[2];
  const float* w_out = (const float*)d_in[3];
  const float* b_out = (const float*)d_in[4];

  char* ws = (char*)d_ws;
  ushort* xs    = (ushort*)ws;
  ushort* ws_in = (ushort*)(ws + 50331648ull);
  ushort* qkv   = (ushort*)(ws + 62914560ull);
  ushort* wos   = (ushort*)(ws + 138412032ull);
  ushort* attn2 = (ushort*)ws;  // alias xs (dead after QKV)

  splitdup_x<<<12288, 256, 0, stream>>>(x, xs);
  split2_w<<<3072, 256, 0, stream>>>(w_in, ws_in);
  split2_w<<<1024, 256, 0, stream>>>(w_out, wos);

  // QKV: [12288 x 3072] = [xh|xh] @ [wh|wl]^T, K'=2048 -> bf16
  gemm8_nt<ushort><<<576, 512, 0, stream>>>(
      xs, ws_in, b_in, qkv, 3072, 2048, 12);

  attn_mfma<<<dim3(4, 3, 128), 256, 0, stream>>>(qkv, attn2);

  // out: [12288 x 1024] = [a|a] @ [wh|wl]^T, K'=2048 -> fp32
  gemm8_nt<float><<<192, 512, 0, stream>>>(
      attn2, wos, b_out, (float*)d_out, 1024, 2048, 4);
}

// Round 7
// 258.819 us; speedup vs baseline: 5.8522x; 1.4161x over previous
//
#include <hip/hip_runtime.h>
#include <hip/hip_bf16.h>

// GraphAttention R7: drop the wl low-word correction everywhere -> plain bf16
// GEMMs with K=1024 (QKV: xh@wh^T, out: attn@wh^T). Error model: each w
// rounding adds ~2e-4 at the output (sqrt(1024)-averaged), budget 3.8e-3.
// 8-phase 256^2 GEMM (R6, conflict-free verified) unchanged; attn no longer
// writes duplicated columns.

#define T_ALL 1536
#define BSZ 8
#define EMBED 1024
#define HEADS 16
#define HDIM 64
#define SEG 512

using bf16 = __hip_bfloat16;
using ushort = unsigned short;
typedef __attribute__((ext_vector_type(8))) short bf16x8;
typedef __attribute__((ext_vector_type(4))) float f32x4;
typedef __attribute__((ext_vector_type(8))) unsigned short ushort8;

__device__ inline float bf2f(ushort u) {
  return __uint_as_float(((unsigned int)u) << 16);
}
__device__ inline ushort f2bf(float f) {
  unsigned int x = __float_as_uint(f);
  x += 0x7fffu + ((x >> 16) & 1u);  // RNE
  return (ushort)(x >> 16);
}

#define GLOAD_LDS16(g, l)                                      \
  __builtin_amdgcn_global_load_lds(                            \
      (const __attribute__((address_space(1))) void*)(g),      \
      (__attribute__((address_space(3))) void*)(l), 16, 0, 0)

// ---------------- prep: flat f32 -> bf16 cast ----------------
__global__ __launch_bounds__(256) void cast_bf16(const float* __restrict__ src,
                                                 ushort* __restrict__ dst) {
  int i4 = blockIdx.x * 256 + threadIdx.x;
  float4 v = *(const float4*)(src + (size_t)i4 * 4);
  ushort4 u;
  u.x = f2bf(v.x); u.y = f2bf(v.y); u.z = f2bf(v.z); u.w = f2bf(v.w);
  *(ushort4*)(dst + (size_t)i4 * 4) = u;
}

// ---------------- 256^2 8-phase MFMA GEMM (R6, unchanged) ----------------
#define BAR_LGKM()                                     \
  __builtin_amdgcn_s_barrier();                        \
  asm volatile("s_waitcnt lgkmcnt(0)" ::: "memory");   \
  __builtin_amdgcn_sched_barrier(0);

#define QUAD(IBASE, JBASE, BF)                                             \
  __builtin_amdgcn_s_setprio(1);                                           \
  _Pragma("unroll")                                                        \
  for (int i = 0; i < 4; ++i) {                                            \
    _Pragma("unroll")                                                      \
    for (int j = 0; j < 2; ++j) {                                          \
      acc[IBASE + i][JBASE + j] = __builtin_amdgcn_mfma_f32_16x16x32_bf16( \
          af[i][0], BF[j][0], acc[IBASE + i][JBASE + j], 0, 0, 0);         \
      acc[IBASE + i][JBASE + j] = __builtin_amdgcn_mfma_f32_16x16x32_bf16( \
          af[i][1], BF[j][1], acc[IBASE + i][JBASE + j], 0, 0, 0);         \
    }                                                                      \
  }                                                                        \
  __builtin_amdgcn_s_setprio(0);

template <typename TC>
__global__ __launch_bounds__(512, 2) void gemm8_nt(
    const ushort* __restrict__ A, const ushort* __restrict__ B,
    const float* __restrict__ bias, TC* __restrict__ C,
    int N, int K, int nN) {
  __shared__ char lds[131072];  // [buf][mat][256 rows * 128 B]
  const int tid = threadIdx.x;
  const int lane = tid & 63, wid = tid >> 6;
  const int wr = wid >> 2, wcn = wid & 3;
  const int r16 = lane & 15, g4 = lane >> 4;

  const int nwg = gridDim.x;
  const int bid = blockIdx.x;
  const int swz = (bid & 7) * (nwg >> 3) + (bid >> 3);
  const int m0 = (swz / nN) * 256, n0 = (swz % nN) * 256;

  const int NT = K >> 6;

  auto STAGE = [&](const ushort* G, int gr0, int ldso, int half, int kcol) {
#pragma unroll
    for (int q = 0; q < 2; ++q) {
      int row = half * 128 + q * 64 + (tid >> 3);
      int sl = (tid & 7) ^ (row & 7);
      const ushort* src = G + (size_t)(gr0 + row) * K + kcol + sl * 8;
      GLOAD_LDS16(src, lds + ldso + row * 128 + (tid & 7) * 16);
    }
  };
  auto LD = [&](int ldso, int row, int kk) -> bf16x8 {
    return *(const bf16x8*)(lds + ldso + row * 128 +
                            ((kk * 64 + g4 * 16) ^ ((row & 7) << 4)));
  };

  f32x4 acc[8][4];
#pragma unroll
  for (int i = 0; i < 8; ++i)
#pragma unroll
    for (int j = 0; j < 4; ++j) acc[i][j] = f32x4{0.f, 0.f, 0.f, 0.f};

  STAGE(A, m0, 0,      0, 0);
  STAGE(B, n0, 32768,  0, 0);
  STAGE(A, m0, 0,      1, 0);
  STAGE(B, n0, 32768,  1, 0);
  if (NT > 1) {
    STAGE(A, m0, 65536, 0, 64);
    STAGE(B, n0, 98304, 0, 64);
    asm volatile("s_waitcnt vmcnt(4)" ::: "memory");
  } else {
    asm volatile("s_waitcnt vmcnt(0)" ::: "memory");
  }
  __builtin_amdgcn_s_barrier();

  bf16x8 af[4][2], bfA[2][2], bfB[2][2];
  int cur = 0;
  for (int t = 0; t < NT; ++t) {
    const int aC = cur * 65536, bC = aC + 32768;
    const int aN = (cur ^ 1) * 65536, bN = aN + 32768;
    // ---- p0
#pragma unroll
    for (int i = 0; i < 4; ++i) {
      int ar = wr * 64 + i * 16 + r16;
      af[i][0] = LD(aC, ar, 0);
      af[i][1] = LD(aC, ar, 1);
    }
#pragma unroll
    for (int j = 0; j < 2; ++j) {
      int br = wcn * 32 + j * 16 + r16;
      bfA[j][0] = LD(bC, br, 0);
      bfA[j][1] = LD(bC, br, 1);
    }
    if (t + 1 < NT) STAGE(A, m0, aN, 1, (t + 1) * 64);
    BAR_LGKM();
    QUAD(0, 0, bfA);
    __builtin_amdgcn_s_barrier();
    // ---- p1
#pragma unroll
    for (int j = 0; j < 2; ++j) {
      int br = wcn * 32 + 128 + j * 16 + r16;
      bfB[j][0] = LD(bC, br, 0);
      bfB[j][1] = LD(bC, br, 1);
    }
    if (t + 1 < NT) STAGE(B, n0, bN, 1, (t + 1) * 64);
    BAR_LGKM();
    QUAD(0, 2, bfB);
    __builtin_amdgcn_s_barrier();
    // ---- p2
#pragma unroll
    for (int i = 0; i < 4; ++i) {
      int ar = wr * 64 + 128 + i * 16 + r16;
      af[i][0] = LD(aC, ar, 0);
      af[i][1] = LD(aC, ar, 1);
    }
    if (t + 2 < NT) STAGE(A, m0, aC, 0, (t + 2) * 64);
    BAR_LGKM();
    QUAD(4, 0, bfA);
    __builtin_amdgcn_s_barrier();
    // ---- p3
    if (t + 2 < NT) {
      STAGE(B, n0, bC, 0, (t + 2) * 64);
      asm volatile("s_waitcnt vmcnt(4)" ::: "memory");
    } else {
      asm volatile("s_waitcnt vmcnt(0)" ::: "memory");
    }
    __builtin_amdgcn_s_barrier();
    QUAD(4, 2, bfB);
    __builtin_amdgcn_s_barrier();
    cur ^= 1;
  }

#pragma unroll
  for (int i = 0; i < 8; ++i) {
    int row = m0 + wr * 64 + (i >> 2) * 128 + (i & 3) * 16 + g4 * 4;
#pragma unroll
    for (int j = 0; j < 4; ++j) {
      int col = n0 + wcn * 32 + (j >> 1) * 128 + (j & 1) * 16 + r16;
      float bs = bias[col];
#pragma unroll
      for (int r = 0; r < 4; ++r) {
        float v = acc[i][j][r] + bs;
        if constexpr (sizeof(TC) == 2)
          ((ushort*)C)[(size_t)(row + r) * N + col] = f2bf(v);
        else
          ((float*)C)[(size_t)(row + r) * N + col] = v;
      }
    }
  }
}

// ---------------- MFMA flash attention (single-copy store) ----------------
__global__ __launch_bounds__(256) void attn_mfma(
    const ushort* __restrict__ qkv,   // [12288][3072] bf16
    ushort* __restrict__ attn) {      // [12288][1024] bf16
  __shared__ ushort Vt[64 * 64];
  __shared__ ushort Ps[128 * 64];
  const int qt = blockIdx.x;
  const int pr = blockIdx.y;
  const int bh = blockIdx.z;
  const int b = bh >> 4, h = bh & 15;
  const int t = threadIdx.x;
  const int lane = t & 63, w = t >> 6;
  const int r16 = lane & 15;
  const int g4 = lane >> 4;
  const int q_t0 = pr * SEG + qt * 128;
  const int k_t0 = ((pr + 1) % 3) * SEG;

  bf16x8 qf[2][2];
#pragma unroll
  for (int i = 0; i < 2; ++i)
#pragma unroll
    for (int ks = 0; ks < 2; ++ks) {
      const ushort* src = qkv +
          ((size_t)(q_t0 + w * 32 + i * 16 + r16) * BSZ + b) * 3072 +
          h * 64 + ks * 32 + g4 * 8;
      ushort8 v = *(const ushort8*)src;
      ushort8 sv;
#pragma unroll
      for (int e = 0; e < 8; ++e) sv[e] = f2bf(bf2f(v[e]) * 0.125f);
      qf[i][ks] = *(bf16x8*)&sv;
    }

  f32x4 acc[2][4];
  float mrow[2][4], lrow[2][4];
#pragma unroll
  for (int i = 0; i < 2; ++i) {
#pragma unroll
    for (int j = 0; j < 4; ++j) acc[i][j] = f32x4{0.f, 0.f, 0.f, 0.f};
#pragma unroll
    for (int r = 0; r < 4; ++r) { mrow[i][r] = -3.0e38f; lrow[i][r] = 0.f; }
  }

  for (int sc8 = 0; sc8 < 8; ++sc8) {
    const int s_base = sc8 * 64;

    bf16x8 kf[4][2];
#pragma unroll
    for (int j = 0; j < 4; ++j)
#pragma unroll
      for (int ks = 0; ks < 2; ++ks) {
        const ushort* src = qkv +
            ((size_t)(k_t0 + s_base + j * 16 + r16) * BSZ + b) * 3072 + 1024 +
            h * 64 + ks * 32 + g4 * 8;
        ushort8 v = *(const ushort8*)src;
        kf[j][ks] = *(bf16x8*)&v;
      }
    const int vd0 = w * 16;
    const ushort* vsrc = qkv +
        ((size_t)(k_t0 + s_base + lane) * BSZ + b) * 3072 + 2048 + h * 64 + vd0;
    ushort8 v0 = *(const ushort8*)vsrc;
    ushort8 v1 = *(const ushort8*)(vsrc + 8);

    f32x4 s4[2][4];
#pragma unroll
    for (int i = 0; i < 2; ++i)
#pragma unroll
      for (int j = 0; j < 4; ++j) {
        f32x4 a = f32x4{0.f, 0.f, 0.f, 0.f};
        a = __builtin_amdgcn_mfma_f32_16x16x32_bf16(qf[i][0], kf[j][0], a, 0, 0, 0);
        a = __builtin_amdgcn_mfma_f32_16x16x32_bf16(qf[i][1], kf[j][1], a, 0, 0, 0);
        s4[i][j] = a;
      }

#pragma unroll
    for (int i = 0; i < 2; ++i)
#pragma unroll
      for (int r = 0; r < 4; ++r) {
        float cm = fmaxf(fmaxf(s4[i][0][r], s4[i][1][r]),
                         fmaxf(s4[i][2][r], s4[i][3][r]));
        cm = fmaxf(cm, __shfl_xor(cm, 1));
        cm = fmaxf(cm, __shfl_xor(cm, 2));
        cm = fmaxf(cm, __shfl_xor(cm, 4));
        cm = fmaxf(cm, __shfl_xor(cm, 8));
        float nm = fmaxf(mrow[i][r], cm);
        float scale = __expf(mrow[i][r] - nm);
        mrow[i][r] = nm;
        float rs = 0.f;
#pragma unroll
        for (int j = 0; j < 4; ++j) {
          float p = __expf(s4[i][j][r] - nm);
          s4[i][j][r] = p;
          rs += p;
        }
        rs += __shfl_xor(rs, 1);
        rs += __shfl_xor(rs, 2);
        rs += __shfl_xor(rs, 4);
        rs += __shfl_xor(rs, 8);
        lrow[i][r] = lrow[i][r] * scale + rs;
#pragma unroll
        for (int j = 0; j < 4; ++j) acc[i][j][r] *= scale;
      }

    __syncthreads();

#pragma unroll
    for (int jj = 0; jj < 16; ++jj) {
      int d = vd0 + jj;
      ushort val = (jj < 8) ? v0[jj] : v1[jj - 8];
      *(ushort*)((char*)Vt + d * 128 + ((lane * 2) ^ ((d & 7) << 4))) = val;
    }
#pragma unroll
    for (int i = 0; i < 2; ++i)
#pragma unroll
      for (int j = 0; j < 4; ++j)
#pragma unroll
        for (int r = 0; r < 4; ++r) {
          int ql = w * 32 + i * 16 + g4 * 4 + r;
          int sl = j * 16 + r16;
          *(ushort*)((char*)Ps + ql * 128 +
                     ((sl * 2) ^ ((ql & 7) << 4))) = f2bf(s4[i][j][r]);
        }
    __syncthreads();

    bf16x8 pa[2][2], vb[4][2];
#pragma unroll
    for (int i = 0; i < 2; ++i)
#pragma unroll
      for (int ks = 0; ks < 2; ++ks) {
        int ql = w * 32 + i * 16 + r16;
        pa[i][ks] = *(bf16x8*)((char*)Ps + ql * 128 +
                               ((ks * 64 + g4 * 16) ^ ((ql & 7) << 4)));
      }
#pragma unroll
    for (int j = 0; j < 4; ++j)
#pragma unroll
      for (int ks = 0; ks < 2; ++ks) {
        int d = j * 16 + r16;
        vb[j][ks] = *(bf16x8*)((char*)Vt + d * 128 +
                               ((ks * 64 + g4 * 16) ^ ((d & 7) << 4)));
      }
#pragma unroll
    for (int i = 0; i < 2; ++i)
#pragma unroll
      for (int j = 0; j < 4; ++j) {
        acc[i][j] = __builtin_amdgcn_mfma_f32_16x16x32_bf16(pa[i][0], vb[j][0],
                                                            acc[i][j], 0, 0, 0);
        acc[i][j] = __builtin_amdgcn_mfma_f32_16x16x32_bf16(pa[i][1], vb[j][1],
                                                            acc[i][j], 0, 0, 0);
      }
  }

#pragma unroll
  for (int i = 0; i < 2; ++i)
#pragma unroll
    for (int r = 0; r < 4; ++r) {
      float inv = 1.f / lrow[i][r];
      int tq = q_t0 + w * 32 + i * 16 + g4 * 4 + r;
      size_t base = ((size_t)tq * BSZ + b) * 1024 + h * 64;
#pragma unroll
      for (int j = 0; j < 4; ++j)
        attn[base + j * 16 + r16] = f2bf(acc[i][j][r] * inv);
    }
}

extern "C" void kernel_launch(void* const* d_in, const int* in_sizes, int n_in,
                              void* d_out, int out_size, void* d_ws,
                              size_t ws_size, hipStream_t stream) {
  const float* x     = (const float*)d_in[0];
  const float* w_in  = (const float*)d_in[1];
  const float* b_in  = (const float*)d_in[2];
  const float* w_out = (const float*)d_in[3];
  const float* b_out = (const float*)d_in[4];

  char* ws = (char*)d_ws;
  // layout: xb 25.2MB | w_inb 6.3MB | qkv 75.5MB | w_outb 2.1MB  (~109MB)
  ushort* xb     = (ushort*)ws;
  ushort* w_inb  = (ushort*)(ws + 25165824ull);
  ushort* qkv    = (ushort*)(ws + 31457280ull);
  ushort* w_outb = (ushort*)(ws + 106954752ull);
  ushort* attn   = (ushort*)ws;  // alias xb (dead after QKV)

  cast_bf16<<<12288, 256, 0, stream>>>(x, xb);        // 12288x1024
  cast_bf16<<<3072, 256, 0, stream>>>(w_in, w_inb);   // 3072x1024
  cast_bf16<<<1024, 256, 0, stream>>>(w_out, w_outb); // 1024x1024

  // QKV: [12288 x 3072] = xb @ w_inb^T, K=1024 -> bf16
  gemm8_nt<ushort><<<576, 512, 0, stream>>>(
      xb, w_inb, b_in, qkv, 3072, 1024, 12);

  attn_mfma<<<dim3(4, 3, 128), 256, 0, stream>>>(qkv, attn);

  // out: [12288 x 1024] = attn @ w_outb^T, K=1024 -> fp32
  gemm8_nt<float><<<192, 512, 0, stream>>>(
      attn, w_outb, b_out, (float*)d_out, 1024, 1024, 4);
}